// Round 1
// baseline (98.152 us; speedup 1.0000x reference)
//
#include <hip/hip_runtime.h>
#include <math.h>

#define MARGIN 1.9f
#define NMAX 1024   // max n supported by the LDS row layout (n=640 here)

// ---------------------------------------------------------------------------
// Fused K1+K2: one block per anchor i.
//   Pass 1: compute row i of the pairwise distance matrix straight from e
//           (e is 320 KB -> fully L2-resident; no dist matrix in memory).
//           FP ordering is bitwise-identical to the previous dist_kernel:
//           sequential float4s, x,y,z,w, one fmaf chain per (i,j), then
//           (acc==0) ? 0 : sqrt(acc).
//   Pass 2: the previous triplet_kernel body, unchanged, reading the row
//           from LDS instead of global.
// Per-block partials go to distinct addresses; visibility to the finalize
// dispatch is provided by the inter-dispatch barrier.
// ---------------------------------------------------------------------------
__global__ __launch_bounds__(256) void fused_triplet_kernel(
        const float* __restrict__ e, const int* __restrict__ lab,
        int n, int d,
        float* __restrict__ part_sum,          // [n]
        unsigned int* __restrict__ part_ne,    // [n]
        unsigned int* __restrict__ part_valid) // [n]
{
    __shared__ float  row[NMAX];
    __shared__ float  pos[NMAX];
    __shared__ int    labs[NMAX];
    __shared__ float4 ei4[128];                // anchor row, supports d<=512
    __shared__ int p_cnt, n_cnt;
    __shared__ float red_s[4];
    __shared__ unsigned int red_c[4];

    const int i    = blockIdx.x;
    const int tid  = threadIdx.x;
    const int lane = tid & 63;
    const int wv   = tid >> 6;
    const int nf4  = d >> 2;                   // float4s per row (32)

    const float4* eg = (const float4*)e;

    if (tid == 0) { p_cnt = 0; n_cnt = 0; }
    for (int k = tid; k < nf4; k += 256) ei4[k] = eg[(size_t)i * nf4 + k];
    for (int j = tid; j < n; j += 256)   labs[j] = lab[j];
    __syncthreads();

    // ---- pass 1: distances. Each thread owns rows j and j+256 (dual acc
    // chains for ILP; the two chains are independent so ordering within each
    // (i,j) pair is unchanged). Lane-private row streaming: each lane reads
    // its own 512B row; the 8 consecutive b128 loads per 128B line hit L1.
    for (int j = tid; j < n; j += 512) {
        const int  jb = j + 256;
        const bool vb = jb < n;
        const float4* rA = eg + (size_t)j * nf4;
        const float4* rB = eg + (size_t)(vb ? jb : j) * nf4;  // garbage slot aliases rA (L1-hot, not stored)
        float accA = 0.f, accB = 0.f;
        #pragma unroll 8
        for (int k = 0; k < nf4; ++k) {
            float4 A  = ei4[k];          // LDS broadcast (free)
            float4 BA = rA[k];
            float4 BB = rB[k];
            float dx;
            dx = A.x - BA.x; accA = fmaf(dx, dx, accA);
            dx = A.y - BA.y; accA = fmaf(dx, dx, accA);
            dx = A.z - BA.z; accA = fmaf(dx, dx, accA);
            dx = A.w - BA.w; accA = fmaf(dx, dx, accA);
            dx = A.x - BB.x; accB = fmaf(dx, dx, accB);
            dx = A.y - BB.y; accB = fmaf(dx, dx, accB);
            dx = A.z - BB.z; accB = fmaf(dx, dx, accB);
            dx = A.w - BB.w; accB = fmaf(dx, dx, accB);
        }
        row[j] = (accA == 0.f) ? 0.f : sqrtf(accA);
        if (vb) row[jb] = (accB == 0.f) ? 0.f : sqrtf(accB);
    }
    __syncthreads();

    // ---- pass 2: per-anchor triplet sweep (identical to the prior K2) ----
    const int my_lab = labs[i];
    int local_neg = 0;
    for (int j = tid; j < n; j += 256) {
        if (labs[j] == my_lab) {
            if (j != i) { int k = atomicAdd(&p_cnt, 1); pos[k] = row[j]; }
        } else {
            local_neg++;
        }
    }
    for (int off = 32; off > 0; off >>= 1) local_neg += __shfl_down(local_neg, off, 64);
    if (lane == 0) atomicAdd(&n_cnt, local_neg);

    // negatives as INF-padded registers (NMAX/256 = 4 slots)
    const float INF = __builtin_huge_valf();
    int j0 = tid, j1 = tid + 256, j2 = tid + 512, j3 = tid + 768;
    float n0 = (j0 < n && labs[j0] != my_lab) ? row[j0] : INF;
    float n1 = (j1 < n && labs[j1] != my_lab) ? row[j1] : INF;
    float n2 = (j2 < n && labs[j2] != my_lab) ? row[j2] : INF;
    float n3 = (j3 < n && labs[j3] != my_lab) ? row[j3] : INF;
    __syncthreads();
    const int P = p_cnt, N = n_cnt;

    float sum = 0.f;
    unsigned int c = 0;
    for (int j = 0; j < P; ++j) {
        float a = pos[j] + MARGIN;        // LDS broadcast
        float t0 = a - n0; if (t0 > 0.f) { sum += t0; c++; }
        float t1 = a - n1; if (t1 > 0.f) { sum += t1; c++; }
        float t2 = a - n2; if (t2 > 0.f) { sum += t2; c++; }
        float t3 = a - n3; if (t3 > 0.f) { sum += t3; c++; }
    }

    for (int off = 32; off > 0; off >>= 1) {
        sum += __shfl_down(sum, off, 64);
        c   += __shfl_down(c,   off, 64);
    }
    if (lane == 0) { red_s[wv] = sum; red_c[wv] = c; }
    __syncthreads();

    if (tid == 0) {
        float s = 0.f; unsigned int cc = 0;
        for (int w = 0; w < 4; ++w) { s += red_s[w]; cc += red_c[w]; }
        part_sum[i]   = s;
        part_ne[i]    = cc;
        part_valid[i] = (unsigned int)P * (unsigned int)N;
    }
}

// ---------------------------------------------------------------------------
// Finalize: reduce n partials -> out[4] = {loss, num_valid, num_non_easy, frac}
// ---------------------------------------------------------------------------
__global__ __launch_bounds__(256) void finalize_kernel(
        const float* __restrict__ part_sum,
        const unsigned int* __restrict__ part_ne,
        const unsigned int* __restrict__ part_valid,
        int nblk, float* __restrict__ out)
{
    __shared__ float red_s[4];
    __shared__ unsigned long long red_ne[4], red_nv[4];
    int tid = threadIdx.x;

    float s = 0.f;
    unsigned long long ne = 0, nv = 0;
    for (int b = tid; b < nblk; b += blockDim.x) {
        s  += part_sum[b];
        ne += part_ne[b];
        nv += part_valid[b];
    }
    for (int off = 32; off > 0; off >>= 1) {
        s  += __shfl_down(s,  off, 64);
        ne += __shfl_down(ne, off, 64);
        nv += __shfl_down(nv, off, 64);
    }
    int wave = tid >> 6;
    if ((tid & 63) == 0) { red_s[wave] = s; red_ne[wave] = ne; red_nv[wave] = nv; }
    __syncthreads();
    if (tid == 0) {
        float ts = 0.f; unsigned long long tne = 0, tnv = 0;
        int nwaves = (blockDim.x + 63) >> 6;
        for (int w = 0; w < nwaves; ++w) { ts += red_s[w]; tne += red_ne[w]; tnv += red_nv[w]; }
        float fne = (float)tne;
        float fnv = (float)tnv;
        out[0] = (fne > 0.f) ? (ts / fmaxf(fne, 1.f)) : 0.f;
        out[1] = fnv;
        out[2] = fne;
        out[3] = fne / (fnv + 1e-16f);
    }
}

extern "C" void kernel_launch(void* const* d_in, const int* in_sizes, int n_in,
                              void* d_out, int out_size, void* d_ws, size_t ws_size,
                              hipStream_t stream) {
    const float* e  = (const float*)d_in[0];
    const int* lab  = (const int*)d_in[1];
    int n = in_sizes[1];           // 640
    int d = in_sizes[0] / n;       // 128

    // ws layout: per-block partials only (no dist matrix anymore)
    char* ws = (char*)d_ws;
    float*        part_sum   = (float*)ws;
    unsigned int* part_ne    = (unsigned int*)(ws + (size_t)n * 4);
    unsigned int* part_valid = (unsigned int*)(ws + (size_t)n * 8);

    fused_triplet_kernel<<<n, 256, 0, stream>>>(e, lab, n, d,
                                                part_sum, part_ne, part_valid);
    finalize_kernel<<<1, 256, 0, stream>>>(part_sum, part_ne, part_valid,
                                           n, (float*)d_out);
}

// Round 2
// 93.866 us; speedup vs baseline: 1.0457x; 1.0457x over previous
//
#include <hip/hip_runtime.h>
#include <math.h>

#define MARGIN 1.9f
#define NMAX 1024   // max n supported by the LDS row layout (n=640 here)
#define TR 64       // rows per staged e-tile
#define TSTRIDE 129 // floats per staged row: 128 + 1 pad -> conflict-free reads

// ---------------------------------------------------------------------------
// Fused K1+K2: one block per anchor i.
//   Pass 1: compute row i of the pairwise distance matrix from e, staging e
//           through LDS in 64-row tiles with COALESCED global loads (the
//           round-1 version read lane-private rows -> 64 lines per load
//           instruction -> latency-bound at 45us). Each row's owner thread
//           then reads its row from LDS sequentially, preserving the exact
//           FP ordering of the original dist kernel bitwise:
//           one fmaf chain per (i,j), k=0..31, x,y,z,w, (acc==0)?0:sqrt.
//           Pad stride 129 floats: compute reads hit 2 lanes/bank (free).
//   Pass 2: the original triplet sweep, unchanged, reading row[] from LDS.
// Per-block partials go to distinct addresses; visibility to the finalize
// dispatch is provided by the inter-dispatch barrier.
// ---------------------------------------------------------------------------
__global__ __launch_bounds__(256) void fused_triplet_kernel(
        const float* __restrict__ e, const int* __restrict__ lab,
        int n, int d,
        float* __restrict__ part_sum,          // [n]
        unsigned int* __restrict__ part_ne,    // [n]
        unsigned int* __restrict__ part_valid) // [n]
{
    __shared__ float  tile[TR * TSTRIDE];      // 33 KB staged e-tile
    __shared__ float  row[NMAX];
    __shared__ float  pos[NMAX];
    __shared__ int    labs[NMAX];
    __shared__ float4 ei4[32];                 // anchor row, d<=128 fast path
    __shared__ int p_cnt, n_cnt;
    __shared__ float red_s[4];
    __shared__ unsigned int red_c[4];

    const int i    = blockIdx.x;
    const int tid  = threadIdx.x;
    const int lane = tid & 63;
    const int wv   = tid >> 6;
    const int nf4  = d >> 2;                   // float4s per row (32)

    const float4* eg = (const float4*)e;

    if (tid == 0) { p_cnt = 0; n_cnt = 0; }
    for (int k = tid; k < nf4 && k < 32; k += 256) ei4[k] = eg[(size_t)i * nf4 + k];
    for (int j = tid; j < n; j += 256)   labs[j] = lab[j];
    // first __syncthreads inside the tile loop covers ei4/labs visibility

    if (nf4 == 32) {
        // ---- pass 1 (fast path, d==128): LDS-tiled coalesced streaming ----
        for (int tb = 0; tb < n; tb += TR) {
            const int rows = (n - tb < TR) ? (n - tb) : TR;
            __syncthreads();                   // tile free of prior readers
            // coalesced load: 64 rows x 32 float4; wave instr = 4 cache lines
            for (int idx = tid; idx < rows * 32; idx += 256) {
                const int r = idx >> 5, c = idx & 31;
                float4 v = eg[(size_t)(tb + r) * 32 + c];
                float* t = &tile[r * TSTRIDE + c * 4];
                t[0] = v.x; t[1] = v.y; t[2] = v.z; t[3] = v.w;
            }
            __syncthreads();
            // owner thread of row tb+rl is tid == (tb & 255) + rl
            const int rl = tid - (tb & 255);
            if (rl >= 0 && rl < rows) {
                const float* tr = &tile[rl * TSTRIDE];
                float acc = 0.f;
                float dx;
                #pragma unroll
                for (int k = 0; k < 32; ++k) {
                    const float4 A = ei4[k];   // LDS broadcast (free)
                    dx = A.x - tr[4*k+0]; acc = fmaf(dx, dx, acc);
                    dx = A.y - tr[4*k+1]; acc = fmaf(dx, dx, acc);
                    dx = A.z - tr[4*k+2]; acc = fmaf(dx, dx, acc);
                    dx = A.w - tr[4*k+3]; acc = fmaf(dx, dx, acc);
                }
                row[tb + rl] = (acc == 0.f) ? 0.f : sqrtf(acc);
            }
        }
    } else {
        // ---- generic fallback (unused for this problem's shapes) ----
        __syncthreads();
        for (int j = tid; j < n; j += 256) {
            const float* rj = e + (size_t)j * d;
            const float* ri = e + (size_t)i * d;
            float acc = 0.f;
            for (int k = 0; k < d; ++k) {
                float dx = ri[k] - rj[k]; acc = fmaf(dx, dx, acc);
            }
            row[j] = (acc == 0.f) ? 0.f : sqrtf(acc);
        }
    }
    __syncthreads();

    // ---- pass 2: per-anchor triplet sweep (identical to prior version) ----
    const int my_lab = labs[i];
    int local_neg = 0;
    for (int j = tid; j < n; j += 256) {
        if (labs[j] == my_lab) {
            if (j != i) { int k = atomicAdd(&p_cnt, 1); pos[k] = row[j]; }
        } else {
            local_neg++;
        }
    }
    for (int off = 32; off > 0; off >>= 1) local_neg += __shfl_down(local_neg, off, 64);
    if (lane == 0) atomicAdd(&n_cnt, local_neg);

    // negatives as INF-padded registers (NMAX/256 = 4 slots)
    const float INF = __builtin_huge_valf();
    int j0 = tid, j1 = tid + 256, j2 = tid + 512, j3 = tid + 768;
    float n0 = (j0 < n && labs[j0] != my_lab) ? row[j0] : INF;
    float n1 = (j1 < n && labs[j1] != my_lab) ? row[j1] : INF;
    float n2 = (j2 < n && labs[j2] != my_lab) ? row[j2] : INF;
    float n3 = (j3 < n && labs[j3] != my_lab) ? row[j3] : INF;
    __syncthreads();
    const int P = p_cnt, N = n_cnt;

    float sum = 0.f;
    unsigned int c = 0;
    for (int j = 0; j < P; ++j) {
        float a = pos[j] + MARGIN;        // LDS broadcast
        float t0 = a - n0; if (t0 > 0.f) { sum += t0; c++; }
        float t1 = a - n1; if (t1 > 0.f) { sum += t1; c++; }
        float t2 = a - n2; if (t2 > 0.f) { sum += t2; c++; }
        float t3 = a - n3; if (t3 > 0.f) { sum += t3; c++; }
    }

    for (int off = 32; off > 0; off >>= 1) {
        sum += __shfl_down(sum, off, 64);
        c   += __shfl_down(c,   off, 64);
    }
    if (lane == 0) { red_s[wv] = sum; red_c[wv] = c; }
    __syncthreads();

    if (tid == 0) {
        float s = 0.f; unsigned int cc = 0;
        for (int w = 0; w < 4; ++w) { s += red_s[w]; cc += red_c[w]; }
        part_sum[i]   = s;
        part_ne[i]    = cc;
        part_valid[i] = (unsigned int)P * (unsigned int)N;
    }
}

// ---------------------------------------------------------------------------
// Finalize: reduce n partials -> out[4] = {loss, num_valid, num_non_easy, frac}
// ---------------------------------------------------------------------------
__global__ __launch_bounds__(256) void finalize_kernel(
        const float* __restrict__ part_sum,
        const unsigned int* __restrict__ part_ne,
        const unsigned int* __restrict__ part_valid,
        int nblk, float* __restrict__ out)
{
    __shared__ float red_s[4];
    __shared__ unsigned long long red_ne[4], red_nv[4];
    int tid = threadIdx.x;

    float s = 0.f;
    unsigned long long ne = 0, nv = 0;
    for (int b = tid; b < nblk; b += blockDim.x) {
        s  += part_sum[b];
        ne += part_ne[b];
        nv += part_valid[b];
    }
    for (int off = 32; off > 0; off >>= 1) {
        s  += __shfl_down(s,  off, 64);
        ne += __shfl_down(ne, off, 64);
        nv += __shfl_down(nv, off, 64);
    }
    int wave = tid >> 6;
    if ((tid & 63) == 0) { red_s[wave] = s; red_ne[wave] = ne; red_nv[wave] = nv; }
    __syncthreads();
    if (tid == 0) {
        float ts = 0.f; unsigned long long tne = 0, tnv = 0;
        int nwaves = (blockDim.x + 63) >> 6;
        for (int w = 0; w < nwaves; ++w) { ts += red_s[w]; tne += red_ne[w]; tnv += red_nv[w]; }
        float fne = (float)tne;
        float fnv = (float)tnv;
        out[0] = (fne > 0.f) ? (ts / fmaxf(fne, 1.f)) : 0.f;
        out[1] = fnv;
        out[2] = fne;
        out[3] = fne / (fnv + 1e-16f);
    }
}

extern "C" void kernel_launch(void* const* d_in, const int* in_sizes, int n_in,
                              void* d_out, int out_size, void* d_ws, size_t ws_size,
                              hipStream_t stream) {
    const float* e  = (const float*)d_in[0];
    const int* lab  = (const int*)d_in[1];
    int n = in_sizes[1];           // 640
    int d = in_sizes[0] / n;       // 128

    // ws layout: per-block partials only
    char* ws = (char*)d_ws;
    float*        part_sum   = (float*)ws;
    unsigned int* part_ne    = (unsigned int*)(ws + (size_t)n * 4);
    unsigned int* part_valid = (unsigned int*)(ws + (size_t)n * 8);

    fused_triplet_kernel<<<n, 256, 0, stream>>>(e, lab, n, d,
                                                part_sum, part_ne, part_valid);
    finalize_kernel<<<1, 256, 0, stream>>>(part_sum, part_ne, part_valid,
                                           n, (float*)d_out);
}

// Round 3
// 82.879 us; speedup vs baseline: 1.1843x; 1.1326x over previous
//
#include <hip/hip_runtime.h>
#include <math.h>

#define MARGIN 1.9f
#define TILE 32
#define NMAX 1024   // max n supported by triplet kernel's LDS layout (n=640)

// ---------------------------------------------------------------------------
// K1: pairwise distance matrix via LDS-tiled "GEMM" on sum((a-b)^2).
// Grid (n/32, n/32), block 256 = 16x16 threads, each computes 2x2 outputs.
// Byte-for-byte the round-0 dist kernel (verified absmax 0.0), plus block
// (0,0) zeroing the ticket counter for K2's last-block finalize.
// ---------------------------------------------------------------------------
__global__ __launch_bounds__(256) void dist_kernel(
        const float* __restrict__ e, int n, int d,
        float* __restrict__ dist,
        unsigned int* __restrict__ done_counter)
{
    __shared__ float As[TILE * 132];
    __shared__ float Bs[TILE * 132];
    const int tid  = threadIdx.x;
    const int row0 = blockIdx.y * TILE;
    const int col0 = blockIdx.x * TILE;
    const int nf4  = d >> 2;                    // float4s per row (32)

    if (blockIdx.x == 0 && blockIdx.y == 0 && tid == 0)
        *done_counter = 0u;                     // visible to K2 via dispatch barrier

    const float4* eg  = (const float4*)e;
    float4* As4 = (float4*)As;
    float4* Bs4 = (float4*)Bs;
    for (int f = tid; f < TILE * nf4; f += 256) {
        int r = f / nf4, c = f - r * nf4;
        int ga = row0 + r; if (ga >= n) ga = n - 1;   // clamp (n%32==0 here)
        int gb = col0 + r; if (gb >= n) gb = n - 1;
        As4[r * 33 + c] = eg[(size_t)ga * nf4 + c];
        Bs4[r * 33 + c] = eg[(size_t)gb * nf4 + c];
    }
    __syncthreads();

    const int tx = tid & 15, ty = tid >> 4;
    float a00 = 0.f, a01 = 0.f, a10 = 0.f, a11 = 0.f;
    for (int t = 0; t < nf4; ++t) {
        float4 A0 = As4[ty * 33 + t];
        float4 A1 = As4[(ty + 16) * 33 + t];
        float4 B0 = Bs4[tx * 33 + t];
        float4 B1 = Bs4[(tx + 16) * 33 + t];
        float dx;
#define ACC(acc, A, B, comp) dx = A.comp - B.comp; acc = fmaf(dx, dx, acc)
        ACC(a00, A0, B0, x); ACC(a00, A0, B0, y); ACC(a00, A0, B0, z); ACC(a00, A0, B0, w);
        ACC(a01, A0, B1, x); ACC(a01, A0, B1, y); ACC(a01, A0, B1, z); ACC(a01, A0, B1, w);
        ACC(a10, A1, B0, x); ACC(a10, A1, B0, y); ACC(a10, A1, B0, z); ACC(a10, A1, B0, w);
        ACC(a11, A1, B1, x); ACC(a11, A1, B1, y); ACC(a11, A1, B1, z); ACC(a11, A1, B1, w);
#undef ACC
    }

    const int r0 = row0 + ty, r1 = row0 + ty + 16;
    const int c0 = col0 + tx, c1 = col0 + tx + 16;
#define EMIT(rr, cc, acc) if ((rr) < n && (cc) < n) \
        dist[(size_t)(rr) * n + (cc)] = ((acc) == 0.f) ? 0.f : sqrtf(acc)
    EMIT(r0, c0, a00); EMIT(r0, c1, a01);
    EMIT(r1, c0, a10); EMIT(r1, c1, a11);
#undef EMIT
}

// ---------------------------------------------------------------------------
// K2: per-anchor triplet sweep (round-0 body, unchanged numerics) + ticketed
// last-block finalize (identical reduction order to the old finalize kernel
// -> bitwise-identical output). Partials go to distinct addresses with plain
// stores; release = __threadfence + device-scope atomicAdd ticket; acquire =
// __threadfence + volatile reads in the last block.
// ---------------------------------------------------------------------------
__global__ __launch_bounds__(256) void triplet_kernel(
        const float* __restrict__ dist, const int* __restrict__ lab, int n,
        float* __restrict__ part_sum,          // [n]
        unsigned int* __restrict__ part_ne,    // [n]
        unsigned int* __restrict__ part_valid, // [n]
        unsigned int* __restrict__ done_counter,
        float* __restrict__ out)               // [4]
{
    __shared__ float row[NMAX];
    __shared__ float pos[NMAX];
    __shared__ int   labs[NMAX];
    __shared__ int p_cnt, n_cnt;
    __shared__ float red_s[4];
    __shared__ unsigned int red_c[4];
    __shared__ unsigned int ticket_s;

    const int i    = blockIdx.x;
    const int tid  = threadIdx.x;
    const int lane = tid & 63;
    const int wv   = tid >> 6;

    if (tid == 0) { p_cnt = 0; n_cnt = 0; }
    for (int j = tid; j < n; j += 256) {
        row[j]  = dist[(size_t)i * n + j];
        labs[j] = lab[j];
    }
    __syncthreads();

    const int my_lab = labs[i];
    int local_neg = 0;
    for (int j = tid; j < n; j += 256) {
        if (labs[j] == my_lab) {
            if (j != i) { int k = atomicAdd(&p_cnt, 1); pos[k] = row[j]; }
        } else {
            local_neg++;
        }
    }
    for (int off = 32; off > 0; off >>= 1) local_neg += __shfl_down(local_neg, off, 64);
    if (lane == 0) atomicAdd(&n_cnt, local_neg);

    // negatives as INF-padded registers (NMAX/256 = 4 slots)
    const float INF = __builtin_huge_valf();
    int j0 = tid, j1 = tid + 256, j2 = tid + 512, j3 = tid + 768;
    float n0 = (j0 < n && labs[j0] != my_lab) ? row[j0] : INF;
    float n1 = (j1 < n && labs[j1] != my_lab) ? row[j1] : INF;
    float n2 = (j2 < n && labs[j2] != my_lab) ? row[j2] : INF;
    float n3 = (j3 < n && labs[j3] != my_lab) ? row[j3] : INF;
    __syncthreads();
    const int P = p_cnt, N = n_cnt;

    float sum = 0.f;
    unsigned int c = 0;
    for (int j = 0; j < P; ++j) {
        float a = pos[j] + MARGIN;        // LDS broadcast
        float t0 = a - n0; if (t0 > 0.f) { sum += t0; c++; }
        float t1 = a - n1; if (t1 > 0.f) { sum += t1; c++; }
        float t2 = a - n2; if (t2 > 0.f) { sum += t2; c++; }
        float t3 = a - n3; if (t3 > 0.f) { sum += t3; c++; }
    }

    for (int off = 32; off > 0; off >>= 1) {
        sum += __shfl_down(sum, off, 64);
        c   += __shfl_down(c,   off, 64);
    }
    if (lane == 0) { red_s[wv] = sum; red_c[wv] = c; }
    __syncthreads();

    if (tid == 0) {
        float s = 0.f; unsigned int cc = 0;
        for (int w = 0; w < 4; ++w) { s += red_s[w]; cc += red_c[w]; }
        part_sum[i]   = s;
        part_ne[i]    = cc;
        part_valid[i] = (unsigned int)P * (unsigned int)N;
        __threadfence();                                   // release partials
        ticket_s = atomicAdd(done_counter, 1u);            // device-scope
    }
    __syncthreads();

    if (ticket_s == (unsigned int)gridDim.x - 1u) {
        // ---- last block: finalize (identical order to old finalize kernel) ----
        __threadfence();                                   // acquire partials
        volatile const float*        vs = (volatile const float*)part_sum;
        volatile const unsigned int* vn = (volatile const unsigned int*)part_ne;
        volatile const unsigned int* vv = (volatile const unsigned int*)part_valid;

        float s = 0.f;
        unsigned long long ne = 0, nv = 0;
        for (int b = tid; b < n; b += 256) {
            s  += vs[b];
            ne += vn[b];
            nv += vv[b];
        }
        for (int off = 32; off > 0; off >>= 1) {
            s  += __shfl_down(s,  off, 64);
            ne += __shfl_down(ne, off, 64);
            nv += __shfl_down(nv, off, 64);
        }
        __shared__ float fr_s[4];
        __shared__ unsigned long long fr_ne[4], fr_nv[4];
        if (lane == 0) { fr_s[wv] = s; fr_ne[wv] = ne; fr_nv[wv] = nv; }
        __syncthreads();
        if (tid == 0) {
            float ts = 0.f; unsigned long long tne = 0, tnv = 0;
            for (int w = 0; w < 4; ++w) { ts += fr_s[w]; tne += fr_ne[w]; tnv += fr_nv[w]; }
            float fne = (float)tne;
            float fnv = (float)tnv;
            out[0] = (fne > 0.f) ? (ts / fmaxf(fne, 1.f)) : 0.f;
            out[1] = fnv;
            out[2] = fne;
            out[3] = fne / (fnv + 1e-16f);
        }
    }
}

extern "C" void kernel_launch(void* const* d_in, const int* in_sizes, int n_in,
                              void* d_out, int out_size, void* d_ws, size_t ws_size,
                              hipStream_t stream) {
    const float* e  = (const float*)d_in[0];
    const int* lab  = (const int*)d_in[1];
    int n = in_sizes[1];           // 640
    int d = in_sizes[0] / n;       // 128

    // ws layout: partials (3 arrays of n) | counter | dist (n*n), 256B aligned
    char* ws = (char*)d_ws;
    float*        part_sum   = (float*)ws;
    unsigned int* part_ne    = (unsigned int*)(ws + (size_t)n * 4);
    unsigned int* part_valid = (unsigned int*)(ws + (size_t)n * 8);
    unsigned int* done_cnt   = (unsigned int*)(ws + (size_t)n * 12);
    size_t dist_off = ((size_t)n * 12 + 4 + 255) & ~(size_t)255;
    float*        dist       = (float*)(ws + dist_off);

    int nt = (n + TILE - 1) / TILE;   // 20
    dim3 grid(nt, nt);
    dist_kernel<<<grid, 256, 0, stream>>>(e, n, d, dist, done_cnt);
    triplet_kernel<<<n, 256, 0, stream>>>(dist, lab, n,
                                          part_sum, part_ne, part_valid,
                                          done_cnt, (float*)d_out);
}